// Round 4
// baseline (55986.011 us; speedup 1.0000x reference)
//
#include <hip/hip_runtime.h>
#include <math.h>

// GRUDetector: B=1024, T=512, F=64, H=128, gates (r,z,n), + MLP head (H->32->1).
// R4: R2/R3 spilled because the allocator targeted 6 waves/EU (VGPR=84) and
// sank the loop-invariant weight loads into the t-loop (62 GB refetch).
// Fix: (1) pin amdgpu_waves_per_eu(3,3) -> budget 170 VGPR, no occupancy
// incentive; (2) cut demand: W_ih moves to LDS (transposed fp32, 98.5 KB,
// conflict-free: lane pairs share g, 32 consecutive g -> 32 banks), W_hh
// half-row = 16 named float4 (64 fp32/thread). Static LDS total 114 KB
// (AMD limit is HW 160 KB). 768 thr = 12 waves = 3/EU, 1 block/CU, 256 blocks.

#define Bsz  1024
#define Tlen 512
#define Fdim 64
#define Hdim 128
#define Gdim 384
#define NB   4
#define NTHR 768
#define WPAD 385   // w_ihT inner pad (bank spread across j)

__device__ __forceinline__ float pair_sum(float v) {
    // add lane^1 partner via DPP quad_perm(1,0,3,2) = 0xB1 (pure VALU)
    int t = __builtin_amdgcn_update_dpp(0, __float_as_int(v), 0xB1, 0xF, 0xF, true);
    return v + __int_as_float(t);
}
__device__ __forceinline__ float fast_sigmoid(float v) {
    return __builtin_amdgcn_rcpf(1.f + __expf(-v));
}
__device__ __forceinline__ float fast_tanh(float v) {
    // 1 - 2/(e^{2v}+1): saturates correctly at +-inf
    return 1.f - 2.f * __builtin_amdgcn_rcpf(__expf(2.f * v) + 1.f);
}

__global__ void
__attribute__((amdgpu_flat_work_group_size(NTHR, NTHR), amdgpu_waves_per_eu(3, 3)))
gru_persist(const float* __restrict__ x,
            const float* __restrict__ W_ih, const float* __restrict__ W_hh,
            const float* __restrict__ b_ih, const float* __restrict__ b_hh,
            const float* __restrict__ W1, const float* __restrict__ b1,
            const float* __restrict__ W2, const float* __restrict__ b2,
            float* __restrict__ out)
{
    __shared__ float w_ihT[Fdim][WPAD];    // 98,560 B  (transposed W_ih)
    __shared__ float h_lds[NB][Hdim];      //  2,048 B
    __shared__ float x_lds[NB][Fdim];      //  1,024 B
    __shared__ float xg_lds[NB][Gdim];     //  6,144 B
    __shared__ float hg_lds[NB][Gdim];     //  6,144 B
    __shared__ float hid_lds[NB][32];      //    512 B   (total ~114.4 KB)

    const int tid = threadIdx.x;
    const int g   = tid >> 1;              // gate row 0..383
    const int hf  = tid & 1;               // half of the dot
    const int b0  = blockIdx.x * NB;
    const int hoff = hf * (Hdim / 2);      // 0 or 64
    const int xoff = hf * (Fdim / 2);      // 0 or 32

    // ---- one-time: W_hh half-row -> 16 named float4 (64 fp32)
    const float4* pb = reinterpret_cast<const float4*>(W_hh + (size_t)g * Hdim + hoff);
    float4 wb0 =pb[0],  wb1 =pb[1],  wb2 =pb[2],  wb3 =pb[3];
    float4 wb4 =pb[4],  wb5 =pb[5],  wb6 =pb[6],  wb7 =pb[7];
    float4 wb8 =pb[8],  wb9 =pb[9],  wb10=pb[10], wb11=pb[11];
    float4 wb12=pb[12], wb13=pb[13], wb14=pb[14], wb15=pb[15];

    const float bi = hf ? 0.f : b_ih[g];   // bias contributed by half 0 only
    const float bh = hf ? 0.f : b_hh[g];

    // ---- one-time: stage W_ih transposed into LDS, init h=0, stage x(t=0)
    for (int i = tid; i < Gdim * Fdim; i += NTHR) {
        int gg = i >> 6, jj = i & 63;      // W_ih row-major read (coalesced)
        w_ihT[jj][gg] = W_ih[i];
    }
    for (int i = tid; i < NB * Hdim; i += NTHR) h_lds[i >> 7][i & 127] = 0.f;
    if (tid < NB * Fdim) {
        int b = tid >> 6, j = tid & 63;
        x_lds[b][j] = x[((size_t)(b0 + b) * Tlen) * Fdim + j];
    }
    __syncthreads();

    // h-side: chunk i covers k = hoff+4i .. +3, weights wb##i
#define HB(i, bb, ACC) { \
    float4 hv = *reinterpret_cast<const float4*>(&h_lds[bb][hoff + 4*(i)]); \
    ACC = fmaf(wb##i.x, hv.x, ACC); ACC = fmaf(wb##i.y, hv.y, ACC); \
    ACC = fmaf(wb##i.z, hv.z, ACC); ACC = fmaf(wb##i.w, hv.w, ACC); }
#define HCHUNK(i) HB(i,0,ha0) HB(i,1,ha1) HB(i,2,ha2) HB(i,3,ha3)

    // x-side: chunk c covers j = xoff+4c .. +3; w from LDS (pair-broadcast)
#define XB(bb, ACC) { \
    float4 xv = *reinterpret_cast<const float4*>(&x_lds[bb][j0]); \
    ACC = fmaf(w0_, xv.x, ACC); ACC = fmaf(w1_, xv.y, ACC); \
    ACC = fmaf(w2_, xv.z, ACC); ACC = fmaf(w3_, xv.w, ACC); }
#define XCHUNK(c) { \
    const int j0 = xoff + 4*(c); \
    float w0_ = w_ihT[j0+0][g], w1_ = w_ihT[j0+1][g]; \
    float w2_ = w_ihT[j0+2][g], w3_ = w_ihT[j0+3][g]; \
    XB(0, xa0) XB(1, xa1) XB(2, xa2) XB(3, xa3) }

    #pragma unroll 1
    for (int t = 0; t < Tlen; ++t) {
        // ---- issue x(t+1) prefetch early (threads 512..767)
        float xpref = 0.f;
        if (tid >= 512 && t + 1 < Tlen) {
            int i = tid - 512, b = i >> 6, j = i & 63;
            xpref = x[((size_t)(b0 + b) * Tlen + (t + 1)) * Fdim + j];
        }

        // ---- GEMV: 8 named accumulators, fully static unroll
        float ha0 = bh, ha1 = bh, ha2 = bh, ha3 = bh;
        float xa0 = bi, xa1 = bi, xa2 = bi, xa3 = bi;
        HCHUNK(0)  HCHUNK(1)  HCHUNK(2)  HCHUNK(3)
        HCHUNK(4)  HCHUNK(5)  HCHUNK(6)  HCHUNK(7)
        HCHUNK(8)  HCHUNK(9)  HCHUNK(10) HCHUNK(11)
        HCHUNK(12) HCHUNK(13) HCHUNK(14) HCHUNK(15)
        XCHUNK(0)  XCHUNK(1)  XCHUNK(2)  XCHUNK(3)
        XCHUNK(4)  XCHUNK(5)  XCHUNK(6)  XCHUNK(7)

        // combine halves (DPP pair add); half0 writes xg, half1 writes hg
        float s;
        s = pair_sum(xa0); if (hf == 0) xg_lds[0][g] = s;
        s = pair_sum(xa1); if (hf == 0) xg_lds[1][g] = s;
        s = pair_sum(xa2); if (hf == 0) xg_lds[2][g] = s;
        s = pair_sum(xa3); if (hf == 0) xg_lds[3][g] = s;
        s = pair_sum(ha0); if (hf == 1) hg_lds[0][g] = s;
        s = pair_sum(ha1); if (hf == 1) hg_lds[1][g] = s;
        s = pair_sum(ha2); if (hf == 1) hg_lds[2][g] = s;
        s = pair_sum(ha3); if (hf == 1) hg_lds[3][g] = s;
        __syncthreads();

        // ---- gates (threads 0..511) ; x(t+1) write-back (threads 512..767)
        if (tid < NB * Hdim) {
            int b = tid >> 7, k = tid & 127;
            float xr = xg_lds[b][k],            hr = hg_lds[b][k];
            float xz = xg_lds[b][Hdim + k],     hz = hg_lds[b][Hdim + k];
            float xn = xg_lds[b][2*Hdim + k],   hn = hg_lds[b][2*Hdim + k];
            float r = fast_sigmoid(xr + hr);
            float z = fast_sigmoid(xz + hz);
            float n = fast_tanh(xn + r * hn);
            h_lds[b][k] = (1.f - z) * n + z * h_lds[b][k];
        } else if (t + 1 < Tlen) {
            int i = tid - 512, b = i >> 6, j = i & 63;
            x_lds[b][j] = xpref;
        }
        __syncthreads();
    }

    // ---- epilogue MLP: hidden = relu(h @ W1.T + b1); out = hidden @ W2.T + b2
    if (tid < NB * 32) {
        int b = tid >> 5, u = tid & 31;
        float a = b1[u];
        #pragma unroll
        for (int k = 0; k < Hdim; ++k) a += W1[u * Hdim + k] * h_lds[b][k];
        hid_lds[b][u] = fmaxf(a, 0.f);
    }
    __syncthreads();
    if (tid < NB) {
        float a = b2[0];
        #pragma unroll
        for (int u = 0; u < 32; ++u) a += W2[u] * hid_lds[tid][u];
        out[b0 + tid] = a;
    }
}

extern "C" void kernel_launch(void* const* d_in, const int* in_sizes, int n_in,
                              void* d_out, int out_size, void* d_ws, size_t ws_size,
                              hipStream_t stream)
{
    const float* x    = (const float*)d_in[0];
    const float* W_ih = (const float*)d_in[1];
    const float* W_hh = (const float*)d_in[2];
    const float* b_ih = (const float*)d_in[3];
    const float* b_hh = (const float*)d_in[4];
    const float* W1   = (const float*)d_in[5];
    const float* b1   = (const float*)d_in[6];
    const float* W2   = (const float*)d_in[7];
    const float* b2   = (const float*)d_in[8];
    float* out = (float*)d_out;

    dim3 grid(Bsz / NB), block(NTHR);
    hipLaunchKernelGGL(gru_persist, grid, block, 0, stream,
                       x, W_ih, W_hh, b_ih, b_hh, W1, b1, W2, b2, out);
}

// Round 5
// 425.343 us; speedup vs baseline: 131.6255x; 131.6255x over previous
//
#include <hip/hip_runtime.h>
#include <math.h>

// GRUDetector: B=1024, T=512, F=64, H=128, gates (r,z,n), + MLP head (H->32->1).
// R5: abandon per-thread register-resident weights (R1-R4 all spilled: compiler
// sinks/spills 64-192 loop-invariant floats across the 512-step loop; 88-100 GB
// scratch HBM traffic). New structure: MFMA 16x16x32_f16 with ALL weights in
// LDS as fp16 (W_hh 96K + W_ih 48K + u 6K = 153.6 KB). NB=16 batch rows/block,
// 64 blocks, 8 waves; wave w owns gate rows 16w..16w+15 of each of r,z,n ->
// 18 MFMAs/wave/step, zero tile waste. fp32 h carried in REGISTERS for the
// z*h path (fp16 h only perturbs dots, suppressed by gate slopes).
// Fragment layouts: C/D col=lane&15,row=(lane>>4)*4+reg (m89-verified);
// A row=lane&15,k=(lane>>4)*8+j ; B col=lane&15,k=(lane>>4)*8+j.

#define Bsz  1024
#define Tlen 512
#define Fdim 64
#define Hdim 128
#define Gdim 384
#define NB   16
#define NTHR 512
#define NBLK (Bsz / NB)   // 64

typedef __attribute__((ext_vector_type(8))) _Float16 f16x8;
typedef __attribute__((ext_vector_type(4))) _Float16 f16x4;
typedef __attribute__((ext_vector_type(2))) _Float16 f16x2;
typedef __attribute__((ext_vector_type(4))) float    f32x4;

__device__ __forceinline__ float fast_sigmoid(float v) {
    return __builtin_amdgcn_rcpf(1.f + __expf(-v));
}
__device__ __forceinline__ float fast_tanh(float v) {
    // 1 - 2/(e^{2v}+1): saturates correctly at +-inf
    return 1.f - 2.f * __builtin_amdgcn_rcpf(__expf(2.f * v) + 1.f);
}

// LDS halfword-index helpers (all compile-time-foldable arithmetic)
//  WH fragment (gate-tile gt 0..23, ktile kt 0..3):  [((gt*4+kt)*4+q)*128 + rr*8 + j]
//  WI fragment (gate-tile gt 0..23, ktile kt 0..1):  [((gt*2+kt)*4+q)*128 + rr*8 + j]
//  U  element (k 0..191, col b 0..15):  [(( (k>>5)*4 + ((k&31)>>3) )*16 + b)*8 + (k&7)]

__global__ __launch_bounds__(NTHR, 2)
void gru_mfma(const float* __restrict__ x,
              const float* __restrict__ W_ih, const float* __restrict__ W_hh,
              const float* __restrict__ b_ih, const float* __restrict__ b_hh,
              const float* __restrict__ W1, const float* __restrict__ b1,
              const float* __restrict__ W2, const float* __restrict__ b2,
              float* __restrict__ out)
{
    __shared__ __align__(16) _Float16 WH[24 * 4 * 4 * 128];  // 98,304 B
    __shared__ __align__(16) _Float16 WI[24 * 2 * 4 * 128];  // 49,152 B
    __shared__ __align__(16) _Float16 U [6 * 4 * 16 * 8];    //  6,144 B (u=[h;x] x 16 cols)

    const int tid  = threadIdx.x;
    const int w    = tid >> 6;        // wave 0..7: owns gate k-range 16w..16w+15
    const int l    = tid & 63;
    const int q    = l >> 4;          // k-group / row-group
    const int bcol = l & 15;          // batch column
    const int b0   = blockIdx.x * NB;

    // ---- one-time: stage W_hh, W_ih into LDS as fp16 in A-fragment layout
    for (int i = tid; i < Gdim * Hdim; i += NTHR) {
        int gr = i >> 7, k = i & 127;
        int idx = (((gr >> 4) * 4 + (k >> 5)) * 4 + ((k & 31) >> 3)) * 128
                + (gr & 15) * 8 + (k & 7);
        WH[idx] = (_Float16)W_hh[i];
    }
    for (int i = tid; i < Gdim * Fdim; i += NTHR) {
        int gr = i >> 6, k = i & 63;
        int idx = (((gr >> 4) * 2 + (k >> 5)) * 4 + ((k & 31) >> 3)) * 128
                + (gr & 15) * 8 + (k & 7);
        WI[idx] = (_Float16)W_ih[i];
    }
    // h region (k<128 -> idx<2048) = 0 ; x(t=0) staged below
    for (int i = tid; i < 2048; i += NTHR) U[i] = (_Float16)0.f;
    {   // stage x(t=0): 1024 elems, 2 per thread
        int e = tid * 2, bx = e >> 6, j = e & 63;
        float2 xv = *reinterpret_cast<const float2*>(
            &x[((size_t)(b0 + bx) * Tlen + 0) * Fdim + j]);
        int kk = 128 + j;
        int idx = (((kk >> 5) * 4 + ((kk & 31) >> 3)) * 16 + bx) * 8 + (kk & 7);
        U[idx]     = (_Float16)xv.x;
        U[idx + 1] = (_Float16)xv.y;
    }

    // ---- per-lane biases (gate rows 16w + q*4 + j)
    float br[4], bz[4], bnh[4], bnx[4];
    #pragma unroll
    for (int j = 0; j < 4; ++j) {
        int gr = 16 * w + q * 4 + j;
        br[j]  = b_ih[gr] + b_hh[gr];
        bz[j]  = b_ih[Hdim + gr] + b_hh[Hdim + gr];
        bnh[j] = b_hh[2 * Hdim + gr];
        bnx[j] = b_ih[2 * Hdim + gr];
    }

    // per-lane h carried in fp32 regs for the z*h path: h[16w+q*4+j][bcol]
    float hp0 = 0.f, hp1 = 0.f, hp2 = 0.f, hp3 = 0.f;

    // h-write address (halfword idx) for this lane's 4 consecutive k's
    const int kb    = 16 * w + 4 * q;
    const int hbase = (((kb >> 5) * 4 + ((kb & 31) >> 3)) * 16 + bcol) * 8 + (kb & 7);

    // x-stage address for this thread (2 elems)
    const int e_x = tid * 2, bx = e_x >> 6, jx = e_x & 63;
    const int kx  = 128 + jx;
    const int xidx = (((kx >> 5) * 4 + ((kx & 31) >> 3)) * 16 + bx) * 8 + (kx & 7);

    __syncthreads();

#define WHF(gt, kt) (*reinterpret_cast<const f16x8*>(&WH[((((gt)*4+(kt))*4+q)*128) + (l&15)*8]))
#define WIF(gt, kt) (*reinterpret_cast<const f16x8*>(&WI[((((gt)*2+(kt))*4+q)*128) + (l&15)*8]))
#define UF(kt)      (*reinterpret_cast<const f16x8*>(&U[(((kt)*4+q)*16 + bcol)*8]))
#define MFMA(a, b, c) __builtin_amdgcn_mfma_f32_16x16x32_f16((a), (b), (c), 0, 0, 0)

    for (int t = 0; t < Tlen; ++t) {
        // B-fragments of u (4 h-tiles + 2 x-tiles)
        f16x8 ub0 = UF(0), ub1 = UF(1), ub2 = UF(2), ub3 = UF(3);
        f16x8 ub4 = UF(4), ub5 = UF(5);

        // prefetch x(t+1) from global (consumed after barrier A)
        float2 xp = {0.f, 0.f};
        if (t + 1 < Tlen)
            xp = *reinterpret_cast<const float2*>(
                &x[((size_t)(b0 + bx) * Tlen + (t + 1)) * Fdim + jx]);

        // C-fragment init = biases (D row = q*4+j matches bias index)
        f32x4 cr  = {br[0],  br[1],  br[2],  br[3]};
        f32x4 cz  = {bz[0],  bz[1],  bz[2],  bz[3]};
        f32x4 cnh = {bnh[0], bnh[1], bnh[2], bnh[3]};
        f32x4 cnx = {bnx[0], bnx[1], bnx[2], bnx[3]};

        // h-side: gates r (gt=w), z (gt=8+w), n (gt=16+w), K = 128 = 4 tiles
        cr  = MFMA(WHF(w,      0), ub0, cr);
        cz  = MFMA(WHF(8 + w,  0), ub0, cz);
        cnh = MFMA(WHF(16 + w, 0), ub0, cnh);
        cr  = MFMA(WHF(w,      1), ub1, cr);
        cz  = MFMA(WHF(8 + w,  1), ub1, cz);
        cnh = MFMA(WHF(16 + w, 1), ub1, cnh);
        cr  = MFMA(WHF(w,      2), ub2, cr);
        cz  = MFMA(WHF(8 + w,  2), ub2, cz);
        cnh = MFMA(WHF(16 + w, 2), ub2, cnh);
        cr  = MFMA(WHF(w,      3), ub3, cr);
        cz  = MFMA(WHF(8 + w,  3), ub3, cz);
        cnh = MFMA(WHF(16 + w, 3), ub3, cnh);
        // x-side: K = 64 = 2 tiles (n goes to separate accumulator cnx)
        cr  = MFMA(WIF(w,      0), ub4, cr);
        cz  = MFMA(WIF(8 + w,  0), ub4, cz);
        cnx = MFMA(WIF(16 + w, 0), ub4, cnx);
        cr  = MFMA(WIF(w,      1), ub5, cr);
        cz  = MFMA(WIF(8 + w,  1), ub5, cz);
        cnx = MFMA(WIF(16 + w, 1), ub5, cnx);

        __syncthreads();   // A: all reads of U complete

        // gates in fp32; h carried in regs (exact direct path)
        float r0 = fast_sigmoid(cr[0]), z0 = fast_sigmoid(cz[0]);
        float r1 = fast_sigmoid(cr[1]), z1 = fast_sigmoid(cz[1]);
        float r2 = fast_sigmoid(cr[2]), z2 = fast_sigmoid(cz[2]);
        float r3 = fast_sigmoid(cr[3]), z3 = fast_sigmoid(cz[3]);
        float n0 = fast_tanh(cnx[0] + r0 * cnh[0]);
        float n1 = fast_tanh(cnx[1] + r1 * cnh[1]);
        float n2 = fast_tanh(cnx[2] + r2 * cnh[2]);
        float n3 = fast_tanh(cnx[3] + r3 * cnh[3]);
        hp0 = (1.f - z0) * n0 + z0 * hp0;
        hp1 = (1.f - z1) * n1 + z1 * hp1;
        hp2 = (1.f - z2) * n2 + z2 * hp2;
        hp3 = (1.f - z3) * n3 + z3 * hp3;

        // write h(t+1) fp16 (4 consecutive halfwords, 8 B aligned)
        f16x4 hq = {(_Float16)hp0, (_Float16)hp1, (_Float16)hp2, (_Float16)hp3};
        *reinterpret_cast<f16x4*>(&U[hbase]) = hq;

        // stage x(t+1)
        if (t + 1 < Tlen) {
            f16x2 xq = {(_Float16)xp.x, (_Float16)xp.y};
            *reinterpret_cast<f16x2*>(&U[xidx]) = xq;
        }
        __syncthreads();   // B: U(t+1) complete
    }

    // ---- epilogue MLP: hidden = relu(hT @ W1.T + b1); out = hidden @ W2.T + b2
    {
        int m = tid & 31, b = tid >> 5;   // hidden unit, batch row
        float acc = b1[m];
        #pragma unroll 8
        for (int k = 0; k < Hdim; ++k) {
            int ui = (((k >> 5) * 4 + ((k & 31) >> 3)) * 16 + b) * 8 + (k & 7);
            acc += W1[m * Hdim + k] * (float)U[ui];
        }
        float v = W2[m] * fmaxf(acc, 0.f);
        v += __shfl_xor(v, 1,  32);
        v += __shfl_xor(v, 2,  32);
        v += __shfl_xor(v, 4,  32);
        v += __shfl_xor(v, 8,  32);
        v += __shfl_xor(v, 16, 32);
        if (m == 0) out[b0 + b] = v + b2[0];
    }
}

extern "C" void kernel_launch(void* const* d_in, const int* in_sizes, int n_in,
                              void* d_out, int out_size, void* d_ws, size_t ws_size,
                              hipStream_t stream)
{
    const float* x    = (const float*)d_in[0];
    const float* W_ih = (const float*)d_in[1];
    const float* W_hh = (const float*)d_in[2];
    const float* b_ih = (const float*)d_in[3];
    const float* b_hh = (const float*)d_in[4];
    const float* W1   = (const float*)d_in[5];
    const float* b1   = (const float*)d_in[6];
    const float* W2   = (const float*)d_in[7];
    const float* b2   = (const float*)d_in[8];
    float* out = (float*)d_out;

    dim3 grid(NBLK), block(NTHR);
    hipLaunchKernelGGL(gru_mfma, grid, block, 0, stream,
                       x, W_ih, W_hh, b_ih, b_hh, W1, b1, W2, b2, out);
}